// Round 2
// baseline (15701.767 us; speedup 1.0000x reference)
//
#include <hip/hip_runtime.h>
#include <stdint.h>

#define BB 32      // batch
#define TT 2048    // timesteps
#define DD 512     // input dim
#define HH 512     // hidden
#define NG 2048    // 4*H gate columns (interleaved: col = hid*4 + gate)

typedef short bf16x8 __attribute__((ext_vector_type(8)));
typedef float f32x4  __attribute__((ext_vector_type(4)));
typedef float f32x16 __attribute__((ext_vector_type(16)));
typedef unsigned long long u64;

__device__ __forceinline__ unsigned short f2bf(float f) {
    union { float f; uint32_t u; } v; v.f = f;
    uint32_t u = v.u;
    return (unsigned short)((u + 0x7fffu + ((u >> 16) & 1u)) >> 16);
}
__device__ __forceinline__ float fast_tanh(float x) {
    float ax = fabsf(x);
    float e = __expf(2.0f * ax);
    float t = 1.0f - 2.0f / (e + 1.0f);
    return copysignf(t, x);
}
__device__ __forceinline__ float fast_sig(float x) {
    return 1.0f / (1.0f + __expf(-x));
}

// ---------------- prep kernels ----------------
__global__ void k_convert_x(const float* __restrict__ X, unsigned short* __restrict__ Xb) {
    int i = (blockIdx.x * 256 + threadIdx.x) * 4;
    float4 v = *(const float4*)(X + i);
    ushort4 o;
    o.x = f2bf(v.x); o.y = f2bf(v.y); o.z = f2bf(v.z); o.w = f2bf(v.w);
    *(ushort4*)(Xb + i) = o;
}

// WpT[n][k] = Wp[k][n]  (512x512)
__global__ void k_prep_wp(const float* __restrict__ Wp, unsigned short* __restrict__ WpT) {
    int idx = blockIdx.x * 256 + threadIdx.x;
    int n = idx >> 9, k = idx & 511;
    WpT[idx] = f2bf(Wp[k * HH + n]);
}

// WtopT[col][k] = Wg[k][hid], UT[col][k] = Wg[H+k][hid]; col = hid*4+g
__global__ void k_prep_u(const float* __restrict__ Wf, const float* __restrict__ Wi,
                         const float* __restrict__ Wc, const float* __restrict__ Wo,
                         const float* __restrict__ bf_, const float* __restrict__ bi_,
                         const float* __restrict__ bc_, const float* __restrict__ bo_,
                         unsigned short* __restrict__ WtopT, unsigned short* __restrict__ UT,
                         float* __restrict__ biascat) {
    int idx = blockIdx.x * 256 + threadIdx.x;   // over NG*512
    int col = idx >> 9, k = idx & 511;
    int g = col & 3, hid = col >> 2;
    const float* W = (g == 0) ? Wf : (g == 1) ? Wi : (g == 2) ? Wc : Wo;
    WtopT[idx] = f2bf(W[k * HH + hid]);
    UT[idx]    = f2bf(W[(HH + k) * HH + hid]);
    if (k == 0) {
        const float* bp = (g == 0) ? bf_ : (g == 1) ? bi_ : (g == 2) ? bc_ : bo_;
        biascat[col] = bp[hid];
    }
}

__global__ void k_zero(unsigned short* __restrict__ hbuf, int* __restrict__ flags) {
    int i = blockIdx.x * 256 + threadIdx.x;   // 128 blocks * 256 = 32768 = 2*BB*HH
    hbuf[i] = 0;
    if (i < 64) flags[i] = 0;
}

// ---------------- phase A: proj = tanh(X @ Wp + bp), stored as 32x32x16 A-fragments ----------------
// projF layout (per t): [ks 0..31][lane 0..63][8 bf16], element (b,h):
//   ks = h>>4, lane = ((h>>3)&1)*32 + b, e = h&7.
// One frag = contiguous 1 KB = one wave-load in the scan.
__global__ __launch_bounds__(256)
void k_gemm_a1(const unsigned short* __restrict__ A, const unsigned short* __restrict__ BT,
               const float* __restrict__ bias, unsigned short* __restrict__ projF,
               int M, int N, int K) {
    __shared__ unsigned short lA[128 * 32];
    __shared__ unsigned short lB[128 * 32];
    const int tid  = threadIdx.x;
    const int wave = tid >> 6, lane = tid & 63;
    const int q = lane >> 4, ln = lane & 15;
    const int tm = blockIdx.x * 128, tn = blockIdx.y * 128;
    const int mtb = (wave >> 1) * 64, ntb = (wave & 1) * 64;
    f32x4 acc[4][4] = {};

    for (int kc = 0; kc < K; kc += 32) {
        __syncthreads();
        #pragma unroll
        for (int r = 0; r < 2; ++r) {
            int row = r * 64 + wave * 16 + (lane >> 2);
            const unsigned short* ga = A  + (size_t)(tm + row) * K + kc + (lane & 3) * 8;
            const unsigned short* gb = BT + (size_t)(tn + row) * K + kc + (lane & 3) * 8;
            __builtin_amdgcn_global_load_lds(
                (const __attribute__((address_space(1))) uint32_t*)ga,
                (__attribute__((address_space(3))) uint32_t*)&lA[(r * 64 + wave * 16) * 32],
                16, 0, 0);
            __builtin_amdgcn_global_load_lds(
                (const __attribute__((address_space(1))) uint32_t*)gb,
                (__attribute__((address_space(3))) uint32_t*)&lB[(r * 64 + wave * 16) * 32],
                16, 0, 0);
        }
        __syncthreads();
        bf16x8 af[4], bfr[4];
        #pragma unroll
        for (int i = 0; i < 4; ++i) {
            af[i]  = *(const bf16x8*)&lA[(mtb + i * 16 + ln) * 32 + q * 8];
            bfr[i] = *(const bf16x8*)&lB[(ntb + i * 16 + ln) * 32 + q * 8];
        }
        #pragma unroll
        for (int mi = 0; mi < 4; ++mi)
            #pragma unroll
            for (int ni = 0; ni < 4; ++ni)
                acc[mi][ni] = __builtin_amdgcn_mfma_f32_16x16x32_bf16(af[mi], bfr[ni], acc[mi][ni], 0, 0, 0);
    }

    #pragma unroll
    for (int ni = 0; ni < 4; ++ni) {
        int col = tn + ntb + ni * 16 + ln;        // hidden index h, 0..511
        float bz = bias[col];
        int hb2 = (col >> 5) * 1024 + ((col >> 4) & 1) * 512
                + ((col >> 3) & 1) * 256 + (col & 7);   // = ks*512 + hi*256 + e (u16)
        #pragma unroll
        for (int mi = 0; mi < 4; ++mi) {
            #pragma unroll
            for (int r = 0; r < 4; ++r) {
                int row = tm + mtb + mi * 16 + q * 4 + r;  // = b*T + t
                int b = row >> 11, t = row & (TT - 1);
                float v = acc[mi][ni][r] + bz;
                projF[(size_t)t * 16384 + hb2 + b * 8] = f2bf(fast_tanh(v));
            }
        }
    }
}

// ---------------- phase B: persistent recurrent kernel ----------------
// 16 blocks x 512 threads (8 waves). Block nb owns gate cols [nb*128,+128) = hidden [nb*32,+32) x 4 gates.
// v3 restructure around mfma_f32_32x32x16_bf16 (batch=32 fits one A-tile):
//   * wave wv: col-tile ct=wv>>1 (32 gate cols), K-half kh=wv&1 (ks = kh*16 + 0..15).
//   * pre-spin: proj_t @ Wtop (16 MFMAs, 2 interleaved chains) — no h dependency, overlaps the wait.
//   * post-spin: h A-frags loaded DIRECTLY from LLC as 16 contiguous 1KB wave-loads (2 u64 bypass
//     atomics/lane each) feeding 16 MFMAs into the SAME accumulators. No LDS staging, no swizzle,
//     no h-read barriers — kills the 256KB/step redundant LDS read + 33.5M bank conflicts of v2.
//   * hbuf is stored FRAGMENT-major (same layout as projF): producers write their u32 (2 cells)
//     at the exact frag position, consumers' loads are fully coalesced.
//   * K-half partial sums exchanged via preact[2][32][132] LDS + one barrier; gates add both halves.
// Coherence protocol unchanged (proven r0/r1): relaxed agent-scope atomics; producer orders h-stores
// before flag via __syncthreads vmcnt drain; consumers order via control dependency on flag spin +
// LLC-bypass loads.
__global__ __launch_bounds__(512, 2)
void k_lstm_seq(const unsigned short* __restrict__ projF,  // [T][32 ks][64 lane][8] bf16
                const unsigned short* __restrict__ WtopT,  // [NG][512] bf16
                const unsigned short* __restrict__ UT,     // [NG][512] bf16
                const float* __restrict__ biascat,         // [NG]
                unsigned short* __restrict__ hbuf,         // [2][32 ks][64 lane][8] bf16 frag-major
                int* __restrict__ flags,                   // [16]
                float* __restrict__ out) {                 // [B][T][H] fp32
    const int nb   = blockIdx.x;           // 0..15
    const int tid  = threadIdx.x;          // 0..511
    const int wv   = tid >> 6;             // wave 0..7
    const int l    = tid & 63;
    const int ct   = wv >> 1;              // col-tile 0..3
    const int kh   = wv & 1;               // K-half
    const int lcol = l & 31;
    const int hi   = l >> 5;

    __shared__ float preact[2][32][132];   // [K-half][batch][local gate col]

    // B-fragments (weights) for this wave's 32 columns x 16 K-steps.
    const size_t wbase = (size_t)(nb * 128 + ct * 32 + lcol) * 512;
    bf16x8 wtf[16], uf[16];
    #pragma unroll
    for (int j = 0; j < 16; ++j) {
        int ks = kh * 16 + j;
        wtf[j] = *(const bf16x8*)(WtopT + wbase + ks * 16 + hi * 8);
        uf[j]  = *(const bf16x8*)(UT    + wbase + ks * 16 + hi * 8);
    }

    // Gate-cell ownership: 2 cells (b0, hl0), (b0, hl0+1) per thread.
    const int b0  = tid >> 4;
    const int hl0 = (tid * 2) & 31;        // even
    float bias8[8];
    #pragma unroll
    for (int k = 0; k < 8; ++k) bias8[k] = biascat[nb * 128 + hl0 * 4 + k];
    float c0 = 0.f, c1 = 0.f;

    // Publish address in frag-major hbuf (u32 units): frag ks = nb*2 + (hl0>>4).
    const int ksc = nb * 2 + (hl0 >> 4);
    const int hic = (hl0 >> 3) & 1;
    const int ec  = hl0 & 7;               // even
    uint32_t* const pub0 = (uint32_t*)hbuf + (size_t)ksc * 256 + (hic * 32 + b0) * 4 + (ec >> 1);

    for (int t = 0; t < TT; ++t) {
        const int rb = (t & 1) ^ 1, wb = t & 1;

        // ---- proj_t @ Wtop: pre-spin (independent of h), 2 interleaved MFMA chains ----
        f32x16 accA = {}, accB = {};
        {
            const unsigned short* pf = projF + (size_t)t * 16384 + (kh * 16) * 512 + l * 8;
            #pragma unroll
            for (int j = 0; j < 16; j += 2) {
                bf16x8 a0 = *(const bf16x8*)(pf + j * 512);
                bf16x8 a1 = *(const bf16x8*)(pf + (j + 1) * 512);
                accA = __builtin_amdgcn_mfma_f32_32x32x16_bf16(a0, wtf[j],     accA, 0, 0, 0);
                accB = __builtin_amdgcn_mfma_f32_32x32x16_bf16(a1, wtf[j + 1], accB, 0, 0, 0);
            }
        }

        // ---- spin until all 16 blocks published h_{t-1} (one flag line) ----
        if (t > 0) {
            int v;
            do {
                v = __hip_atomic_load(&flags[l & 15], __ATOMIC_RELAXED, __HIP_MEMORY_SCOPE_AGENT);
            } while (!__all(v >= t));
        }

        // ---- h_{t-1} @ U: 16 contiguous 1KB frag loads direct from LLC, then MFMAs ----
        {
            const u64* hb = (const u64*)hbuf + (size_t)rb * 4096 + (kh * 16) * 128 + l * 2;
            union { bf16x8 v; u64 d[2]; } hf[16];
            #pragma unroll
            for (int j = 0; j < 16; ++j) {
                hf[j].d[0] = __hip_atomic_load(hb + j * 128,     __ATOMIC_RELAXED, __HIP_MEMORY_SCOPE_AGENT);
                hf[j].d[1] = __hip_atomic_load(hb + j * 128 + 1, __ATOMIC_RELAXED, __HIP_MEMORY_SCOPE_AGENT);
            }
            #pragma unroll
            for (int j = 0; j < 16; j += 2) {
                accA = __builtin_amdgcn_mfma_f32_32x32x16_bf16(hf[j].v,     uf[j],     accA, 0, 0, 0);
                accB = __builtin_amdgcn_mfma_f32_32x32x16_bf16(hf[j + 1].v, uf[j + 1], accB, 0, 0, 0);
            }
        }

        // ---- write K-half partial: D row = (reg&3) + 8*(reg>>2) + 4*hi, col = lane&31 ----
        #pragma unroll
        for (int reg = 0; reg < 16; ++reg) {
            int b = (reg & 3) + 8 * (reg >> 2) + 4 * hi;
            preact[kh][b][ct * 32 + lcol] = accA[reg] + accB[reg];
        }
        __syncthreads();

        // ---- gates: sum both K-halves + bias for the 2 owned cells ----
        const float* p0 = &preact[0][b0][hl0 * 4];
        const float* p1 = &preact[1][b0][hl0 * 4];
        float f0 = fast_sig (p0[0] + p1[0] + bias8[0]);
        float i0 = fast_sig (p0[1] + p1[1] + bias8[1]);
        float g0 = fast_tanh(p0[2] + p1[2] + bias8[2]);
        float o0 = fast_sig (p0[3] + p1[3] + bias8[3]);
        c0 = f0 * c0 + i0 * g0;
        float h0 = o0 * fast_tanh(c0);

        float f1 = fast_sig (p0[4] + p1[4] + bias8[4]);
        float i1 = fast_sig (p0[5] + p1[5] + bias8[5]);
        float g1 = fast_tanh(p0[6] + p1[6] + bias8[6]);
        float o1 = fast_sig (p0[7] + p1[7] + bias8[7]);
        c1 = f1 * c1 + i1 * g1;
        float h1 = o1 * fast_tanh(c1);

        // ---- h exchange: one u32 write-through store at the frag-major position ----
        uint32_t packed = (uint32_t)f2bf(h0) | ((uint32_t)f2bf(h1) << 16);
        __hip_atomic_store(pub0 + (size_t)wb * 8192, packed,
                           __ATOMIC_RELAXED, __HIP_MEMORY_SCOPE_AGENT);

        __syncthreads();   // barrier drain (vmcnt 0): h stores LLC-visible; preact reads done
        if (tid == 0)
            __hip_atomic_store(&flags[nb], t + 1, __ATOMIC_RELAXED, __HIP_MEMORY_SCOPE_AGENT);

        // ---- output store AFTER publish: off the inter-block critical path ----
        float2 ho; ho.x = h0; ho.y = h1;
        *(float2*)&out[((size_t)b0 * TT + t) * HH + nb * 32 + hl0] = ho;
    }
}

// ---------------- launcher ----------------
extern "C" void kernel_launch(void* const* d_in, const int* in_sizes, int n_in,
                              void* d_out, int out_size, void* d_ws, size_t ws_size,
                              hipStream_t stream) {
    const float* X   = (const float*)d_in[0];
    const float* Wp  = (const float*)d_in[1];
    const float* bp  = (const float*)d_in[2];
    const float* Wf  = (const float*)d_in[3];
    const float* bf_ = (const float*)d_in[4];
    const float* Wi  = (const float*)d_in[5];
    const float* bi_ = (const float*)d_in[6];
    const float* Wc  = (const float*)d_in[7];
    const float* bc_ = (const float*)d_in[8];
    const float* Wo  = (const float*)d_in[9];
    const float* bo_ = (const float*)d_in[10];
    float* out = (float*)d_out;

    char* w = (char*)d_ws;
    auto alloc = [&](size_t bytes) {
        char* p = w;
        w += (bytes + 255) & ~(size_t)255;
        return p;
    };
    unsigned short* projF  = (unsigned short*)alloc((size_t)BB * TT * HH * 2); // 64 MB fragment-major
    unsigned short* WpT    = (unsigned short*)alloc((size_t)DD * HH * 2);      // 0.5 MB
    unsigned short* WtopT  = (unsigned short*)alloc((size_t)NG * HH * 2);      // 2 MB
    unsigned short* UT     = (unsigned short*)alloc((size_t)NG * HH * 2);      // 2 MB
    float*          biascat= (float*)alloc(NG * 4);
    unsigned short* hbuf   = (unsigned short*)alloc(2 * BB * HH * 2);          // frag-major, dbl-buf
    int*            flags  = (int*)alloc(1024);

    // Xb (bf16 X, 64 MB) borrows d_out (128 MB): consumed by k_gemm_a1 before phase B writes out.
    unsigned short* Xb = (unsigned short*)d_out;

    k_convert_x<<<(BB * TT * DD) / (256 * 4), 256, 0, stream>>>(X, Xb);
    k_prep_wp<<<(DD * HH) / 256, 256, 0, stream>>>(Wp, WpT);
    k_prep_u<<<(NG * HH) / 256, 256, 0, stream>>>(Wf, Wi, Wc, Wo, bf_, bi_, bc_, bo_,
                                                  WtopT, UT, biascat);
    k_zero<<<128, 256, 0, stream>>>(hbuf, flags);

    // proj fragment-major = tanh(X @ Wp + bp)
    k_gemm_a1<<<dim3((BB * TT) / 128, HH / 128), 256, 0, stream>>>(Xb, WpT, bp, projF,
                                                                   BB * TT, HH, DD);
    // sequential scan: 16 blocks x 512 threads, 32x32x16 MFMA, LLC-direct frag h exchange
    k_lstm_seq<<<16, 512, 0, stream>>>(projF, WtopT, UT, biascat, hbuf, flags, out);
}

// Round 3
// 12872.675 us; speedup vs baseline: 1.2198x; 1.2198x over previous
//
#include <hip/hip_runtime.h>
#include <stdint.h>

#define BB 32      // batch
#define TT 2048    // timesteps
#define DD 512     // input dim
#define HH 512     // hidden
#define NG 2048    // 4*H gate columns (interleaved: col = hid*4 + gate)

typedef short bf16x8 __attribute__((ext_vector_type(8)));
typedef float f32x4  __attribute__((ext_vector_type(4)));
typedef float f32x16 __attribute__((ext_vector_type(16)));
typedef unsigned long long u64;

__device__ __forceinline__ unsigned short f2bf(float f) {
    union { float f; uint32_t u; } v; v.f = f;
    uint32_t u = v.u;
    return (unsigned short)((u + 0x7fffu + ((u >> 16) & 1u)) >> 16);
}
__device__ __forceinline__ float fast_tanh(float x) {
    float ax = fabsf(x);
    float e = __expf(2.0f * ax);
    float t = 1.0f - 2.0f / (e + 1.0f);
    return copysignf(t, x);
}
__device__ __forceinline__ float fast_sig(float x) {
    return 1.0f / (1.0f + __expf(-x));
}

// ---------------- prep kernels ----------------
__global__ void k_convert_x(const float* __restrict__ X, unsigned short* __restrict__ Xb) {
    int i = (blockIdx.x * 256 + threadIdx.x) * 4;
    float4 v = *(const float4*)(X + i);
    ushort4 o;
    o.x = f2bf(v.x); o.y = f2bf(v.y); o.z = f2bf(v.z); o.w = f2bf(v.w);
    *(ushort4*)(Xb + i) = o;
}

// WpT[n][k] = Wp[k][n]  (512x512)
__global__ void k_prep_wp(const float* __restrict__ Wp, unsigned short* __restrict__ WpT) {
    int idx = blockIdx.x * 256 + threadIdx.x;
    int n = idx >> 9, k = idx & 511;
    WpT[idx] = f2bf(Wp[k * HH + n]);
}

// WtopT[col][k] = Wg[k][hid], UT[col][k] = Wg[H+k][hid]; col = hid*4+g
__global__ void k_prep_u(const float* __restrict__ Wf, const float* __restrict__ Wi,
                         const float* __restrict__ Wc, const float* __restrict__ Wo,
                         const float* __restrict__ bf_, const float* __restrict__ bi_,
                         const float* __restrict__ bc_, const float* __restrict__ bo_,
                         unsigned short* __restrict__ WtopT, unsigned short* __restrict__ UT,
                         float* __restrict__ biascat) {
    int idx = blockIdx.x * 256 + threadIdx.x;   // over NG*512
    int col = idx >> 9, k = idx & 511;
    int g = col & 3, hid = col >> 2;
    const float* W = (g == 0) ? Wf : (g == 1) ? Wi : (g == 2) ? Wc : Wo;
    WtopT[idx] = f2bf(W[k * HH + hid]);
    UT[idx]    = f2bf(W[(HH + k) * HH + hid]);
    if (k == 0) {
        const float* bp = (g == 0) ? bf_ : (g == 1) ? bi_ : (g == 2) ? bc_ : bo_;
        biascat[col] = bp[hid];
    }
}

__global__ void k_zero(unsigned short* __restrict__ hbuf, int* __restrict__ flags) {
    int i = blockIdx.x * 256 + threadIdx.x;   // 128 blocks * 256 = 32768 = 2*BB*HH
    hbuf[i] = 0;
    if (i < 64) flags[i] = 0;
}

// ---------------- phase A: proj = tanh(X @ Wp + bp), stored as 32x32x16 A-fragments ----------------
// projF layout (per t): [ks 0..31][lane 0..63][8 bf16], element (b,h):
//   ks = h>>4, lane = ((h>>3)&1)*32 + b, e = h&7.
// One frag = contiguous 1 KB = one wave-load in the scan.  (PROVEN r2)
__global__ __launch_bounds__(256)
void k_gemm_a1(const unsigned short* __restrict__ A, const unsigned short* __restrict__ BT,
               const float* __restrict__ bias, unsigned short* __restrict__ projF,
               int M, int N, int K) {
    __shared__ unsigned short lA[128 * 32];
    __shared__ unsigned short lB[128 * 32];
    const int tid  = threadIdx.x;
    const int wave = tid >> 6, lane = tid & 63;
    const int q = lane >> 4, ln = lane & 15;
    const int tm = blockIdx.x * 128, tn = blockIdx.y * 128;
    const int mtb = (wave >> 1) * 64, ntb = (wave & 1) * 64;
    f32x4 acc[4][4] = {};

    for (int kc = 0; kc < K; kc += 32) {
        __syncthreads();
        #pragma unroll
        for (int r = 0; r < 2; ++r) {
            int row = r * 64 + wave * 16 + (lane >> 2);
            const unsigned short* ga = A  + (size_t)(tm + row) * K + kc + (lane & 3) * 8;
            const unsigned short* gb = BT + (size_t)(tn + row) * K + kc + (lane & 3) * 8;
            __builtin_amdgcn_global_load_lds(
                (const __attribute__((address_space(1))) uint32_t*)ga,
                (__attribute__((address_space(3))) uint32_t*)&lA[(r * 64 + wave * 16) * 32],
                16, 0, 0);
            __builtin_amdgcn_global_load_lds(
                (const __attribute__((address_space(1))) uint32_t*)gb,
                (__attribute__((address_space(3))) uint32_t*)&lB[(r * 64 + wave * 16) * 32],
                16, 0, 0);
        }
        __syncthreads();
        bf16x8 af[4], bfr[4];
        #pragma unroll
        for (int i = 0; i < 4; ++i) {
            af[i]  = *(const bf16x8*)&lA[(mtb + i * 16 + ln) * 32 + q * 8];
            bfr[i] = *(const bf16x8*)&lB[(ntb + i * 16 + ln) * 32 + q * 8];
        }
        #pragma unroll
        for (int mi = 0; mi < 4; ++mi)
            #pragma unroll
            for (int ni = 0; ni < 4; ++ni)
                acc[mi][ni] = __builtin_amdgcn_mfma_f32_16x16x32_bf16(af[mi], bfr[ni], acc[mi][ni], 0, 0, 0);
    }

    #pragma unroll
    for (int ni = 0; ni < 4; ++ni) {
        int col = tn + ntb + ni * 16 + ln;        // hidden index h, 0..511
        float bz = bias[col];
        int hb2 = (col >> 5) * 1024 + ((col >> 4) & 1) * 512
                + ((col >> 3) & 1) * 256 + (col & 7);   // = ks*512 + hi*256 + e (u16)
        #pragma unroll
        for (int mi = 0; mi < 4; ++mi) {
            #pragma unroll
            for (int r = 0; r < 4; ++r) {
                int row = tm + mtb + mi * 16 + q * 4 + r;  // = b*T + t
                int b = row >> 11, t = row & (TT - 1);
                float v = acc[mi][ni][r] + bz;
                projF[(size_t)t * 16384 + hb2 + b * 8] = f2bf(fast_tanh(v));
            }
        }
    }
}

// ---------------- phase B: persistent recurrent kernel ----------------
// 16 blocks x 512 threads. Block nb owns gate cols [nb*128,+128).
// v4 = r1's LDS-staged h exchange + r2's 32x32x16 fragment math + three fixes:
//   * hbuf frag-major (proven r2 publish) => LDS staging is a LINEAR 32KB copy and every
//     fragment read is a contiguous 1KB stride-1 ds_read_b128 — conflict-free WITHOUT swizzle.
//     LLC h-read traffic stays 32KB/block/step (r2's LLC-direct 128KB was the regression).
//   * weight fragments pinned via empty inline-asm "+v": non-rematerializable => register-resident
//     (r1/r2 silently reloaded 128 VGPRs of weights from L2 every step; VGPR_Count 104/116 betrayed it).
//   * wave-0-only flag spin + __syncthreads release: 8x less poll traffic on the flag line.
// Coherence protocol unchanged (proven r0-r2): relaxed agent-scope atomics; producer orders h-stores
// before flag via __syncthreads vmcnt drain; consumers order via control dep on spin + barrier,
// loads LLC-bypass so no stale L1/L2 data.
__global__ __launch_bounds__(512, 2)
void k_lstm_seq(const unsigned short* __restrict__ projF,  // [T][32 ks][64 lane][8] bf16
                const unsigned short* __restrict__ WtopT,  // [NG][512] bf16
                const unsigned short* __restrict__ UT,     // [NG][512] bf16
                const float* __restrict__ biascat,         // [NG]
                unsigned short* __restrict__ hbuf,         // [2][32 ks][64 lane][8] bf16 frag-major
                int* __restrict__ flags,                   // [16]
                float* __restrict__ out) {                 // [B][T][H] fp32
    const int nb   = blockIdx.x;           // 0..15
    const int tid  = threadIdx.x;          // 0..511
    const int wv   = tid >> 6;             // wave 0..7
    const int l    = tid & 63;
    const int ct   = wv >> 1;              // col-tile 0..3
    const int kh   = wv & 1;               // K-half
    const int lcol = l & 31;
    const int hi   = l >> 5;

    __shared__ __align__(16) unsigned short lh[16384];  // 32KB staged h, frag-major LINEAR
    __shared__ float preact[2][32][132];                // [K-half][batch][local gate col]

    // B-fragments (weights) for this wave's 32 columns x 16 K-steps. (mapping proven r2)
    const size_t wbase = (size_t)(nb * 128 + ct * 32 + lcol) * 512;
    bf16x8 wtf[16], uf[16];
    #pragma unroll
    for (int j = 0; j < 16; ++j) {
        int ks = kh * 16 + j;
        wtf[j] = *(const bf16x8*)(WtopT + wbase + ks * 16 + hi * 8);
        uf[j]  = *(const bf16x8*)(UT    + wbase + ks * 16 + hi * 8);
    }
    // Pin: opaque to the optimizer => cannot be rematerialized (reloaded) inside the loop.
    #pragma unroll
    for (int j = 0; j < 16; ++j) {
        asm volatile("" : "+v"(wtf[j]));
        asm volatile("" : "+v"(uf[j]));
    }

    // Gate-cell ownership: 2 cells (b0, hl0), (b0, hl0+1) per thread. (proven r2)
    const int b0  = tid >> 4;
    const int hl0 = (tid * 2) & 31;        // even
    float bias8[8];
    #pragma unroll
    for (int k = 0; k < 8; ++k) bias8[k] = biascat[nb * 128 + hl0 * 4 + k];
    float c0 = 0.f, c1 = 0.f;

    // Publish address in frag-major hbuf (u32 units): frag ks = nb*2 + (hl0>>4). (proven r2)
    const int ksc = nb * 2 + (hl0 >> 4);
    const int hic = (hl0 >> 3) & 1;
    const int ec  = hl0 & 7;               // even
    uint32_t* const pub0 = (uint32_t*)hbuf + (size_t)ksc * 256 + (hic * 32 + b0) * 4 + (ec >> 1);

    for (int t = 0; t < TT; ++t) {
        const int rb = (t & 1) ^ 1, wb = t & 1;

        // ---- proj_t @ Wtop: pre-spin (independent of h), overlaps flag propagation ----
        f32x16 acc = {};
        {
            const unsigned short* pf = projF + (size_t)t * 16384 + (kh * 16) * 512 + l * 8;
            #pragma unroll
            for (int j = 0; j < 16; ++j) {
                bf16x8 a = *(const bf16x8*)(pf + j * 512);
                acc = __builtin_amdgcn_mfma_f32_32x32x16_bf16(a, wtf[j], acc, 0, 0, 0);
            }
        }

        // ---- wave-0-only spin; barrier releases the block ----
        if (t > 0 && wv == 0) {
            int v;
            do {
                v = __hip_atomic_load(&flags[l & 15], __ATOMIC_RELAXED, __HIP_MEMORY_SCOPE_AGENT);
            } while (!__all(v >= t));
        }
        __syncthreads();

        // ---- stage h_{t-1} (32KB, frag-major) into LDS: linear coalesced copy ----
        {
            const u64* hb = (const u64*)hbuf + (size_t)rb * 4096;
            u64 st[8];
            #pragma unroll
            for (int r = 0; r < 8; ++r)
                st[r] = __hip_atomic_load(hb + r * 512 + tid, __ATOMIC_RELAXED, __HIP_MEMORY_SCOPE_AGENT);
            u64* lh64 = (u64*)lh;
            #pragma unroll
            for (int r = 0; r < 8; ++r)
                lh64[r * 512 + tid] = st[r];
        }
        __syncthreads();

        // ---- h_{t-1} @ U from LDS: contiguous 1KB frag reads (stride-1, conflict-free) ----
        {
            const char* lbase = (const char*)lh + (kh * 16) * 1024 + l * 16;
            #pragma unroll
            for (int j = 0; j < 16; ++j) {
                bf16x8 a = *(const bf16x8*)(lbase + j * 1024);
                acc = __builtin_amdgcn_mfma_f32_32x32x16_bf16(a, uf[j], acc, 0, 0, 0);
            }
        }

        // ---- write K-half partial: D row = (reg&3) + 8*(reg>>2) + 4*hi, col = lane&31 ----
        #pragma unroll
        for (int reg = 0; reg < 16; ++reg) {
            int b = (reg & 3) + 8 * (reg >> 2) + 4 * hi;
            preact[kh][b][ct * 32 + lcol] = acc[reg];
        }
        __syncthreads();

        // ---- gates: sum both K-halves + bias for the 2 owned cells ----
        const float* p0 = &preact[0][b0][hl0 * 4];
        const float* p1 = &preact[1][b0][hl0 * 4];
        float f0 = fast_sig (p0[0] + p1[0] + bias8[0]);
        float i0 = fast_sig (p0[1] + p1[1] + bias8[1]);
        float g0 = fast_tanh(p0[2] + p1[2] + bias8[2]);
        float o0 = fast_sig (p0[3] + p1[3] + bias8[3]);
        c0 = f0 * c0 + i0 * g0;
        float h0 = o0 * fast_tanh(c0);

        float f1 = fast_sig (p0[4] + p1[4] + bias8[4]);
        float i1 = fast_sig (p0[5] + p1[5] + bias8[5]);
        float g1 = fast_tanh(p0[6] + p1[6] + bias8[6]);
        float o1 = fast_sig (p0[7] + p1[7] + bias8[7]);
        c1 = f1 * c1 + i1 * g1;
        float h1 = o1 * fast_tanh(c1);

        // ---- h exchange: one u32 write-through store at the frag-major position ----
        uint32_t packed = (uint32_t)f2bf(h0) | ((uint32_t)f2bf(h1) << 16);
        __hip_atomic_store(pub0 + (size_t)wb * 8192, packed,
                           __ATOMIC_RELAXED, __HIP_MEMORY_SCOPE_AGENT);

        __syncthreads();   // barrier drain (vmcnt 0): h stores LLC-visible; preact reads done
        if (tid == 0)
            __hip_atomic_store(&flags[nb], t + 1, __ATOMIC_RELAXED, __HIP_MEMORY_SCOPE_AGENT);

        // ---- output store AFTER publish: off the inter-block critical path ----
        float2 ho; ho.x = h0; ho.y = h1;
        *(float2*)&out[((size_t)b0 * TT + t) * HH + nb * 32 + hl0] = ho;
    }
}

// ---------------- launcher ----------------
extern "C" void kernel_launch(void* const* d_in, const int* in_sizes, int n_in,
                              void* d_out, int out_size, void* d_ws, size_t ws_size,
                              hipStream_t stream) {
    const float* X   = (const float*)d_in[0];
    const float* Wp  = (const float*)d_in[1];
    const float* bp  = (const float*)d_in[2];
    const float* Wf  = (const float*)d_in[3];
    const float* bf_ = (const float*)d_in[4];
    const float* Wi  = (const float*)d_in[5];
    const float* bi_ = (const float*)d_in[6];
    const float* Wc  = (const float*)d_in[7];
    const float* bc_ = (const float*)d_in[8];
    const float* Wo  = (const float*)d_in[9];
    const float* bo_ = (const float*)d_in[10];
    float* out = (float*)d_out;

    char* w = (char*)d_ws;
    auto alloc = [&](size_t bytes) {
        char* p = w;
        w += (bytes + 255) & ~(size_t)255;
        return p;
    };
    unsigned short* projF  = (unsigned short*)alloc((size_t)BB * TT * HH * 2); // 64 MB fragment-major
    unsigned short* WpT    = (unsigned short*)alloc((size_t)DD * HH * 2);      // 0.5 MB
    unsigned short* WtopT  = (unsigned short*)alloc((size_t)NG * HH * 2);      // 2 MB
    unsigned short* UT     = (unsigned short*)alloc((size_t)NG * HH * 2);      // 2 MB
    float*          biascat= (float*)alloc(NG * 4);
    unsigned short* hbuf   = (unsigned short*)alloc(2 * BB * HH * 2);          // frag-major, dbl-buf
    int*            flags  = (int*)alloc(1024);

    // Xb (bf16 X, 64 MB) borrows d_out (128 MB): consumed by k_gemm_a1 before phase B writes out.
    unsigned short* Xb = (unsigned short*)d_out;

    k_convert_x<<<(BB * TT * DD) / (256 * 4), 256, 0, stream>>>(X, Xb);
    k_prep_wp<<<(DD * HH) / 256, 256, 0, stream>>>(Wp, WpT);
    k_prep_u<<<(NG * HH) / 256, 256, 0, stream>>>(Wf, Wi, Wc, Wo, bf_, bi_, bc_, bo_,
                                                  WtopT, UT, biascat);
    k_zero<<<128, 256, 0, stream>>>(hbuf, flags);

    // proj fragment-major = tanh(X @ Wp + bp)
    k_gemm_a1<<<dim3((BB * TT) / 128, HH / 128), 256, 0, stream>>>(Xb, WpT, bp, projF,
                                                                   BB * TT, HH, DD);
    // sequential scan: LDS-staged frag-major h exchange, pinned weights, wave-0 spin
    k_lstm_seq<<<16, 512, 0, stream>>>(projF, WtopT, UT, biascat, hbuf, flags, out);
}

// Round 4
// 6829.806 us; speedup vs baseline: 2.2990x; 1.8848x over previous
//
#include <hip/hip_runtime.h>
#include <stdint.h>

#define BB 32      // batch
#define TT 2048    // timesteps
#define DD 512     // input dim
#define HH 512     // hidden
#define NG 2048    // 4*H gate columns (interleaved: col = hid*4 + gate)

typedef short bf16x8 __attribute__((ext_vector_type(8)));
typedef float f32x4  __attribute__((ext_vector_type(4)));
typedef float f32x16 __attribute__((ext_vector_type(16)));
typedef unsigned long long u64;

__device__ __forceinline__ unsigned short f2bf(float f) {
    union { float f; uint32_t u; } v; v.f = f;
    uint32_t u = v.u;
    return (unsigned short)((u + 0x7fffu + ((u >> 16) & 1u)) >> 16);
}
__device__ __forceinline__ float fast_tanh(float x) {
    float ax = fabsf(x);
    float e = __expf(2.0f * ax);
    float t = 1.0f - 2.0f / (e + 1.0f);
    return copysignf(t, x);
}
__device__ __forceinline__ float fast_sig(float x) {
    return 1.0f / (1.0f + __expf(-x));
}

// ---------------- prep kernels ----------------
__global__ void k_convert_x(const float* __restrict__ X, unsigned short* __restrict__ Xb) {
    int i = (blockIdx.x * 256 + threadIdx.x) * 4;
    float4 v = *(const float4*)(X + i);
    ushort4 o;
    o.x = f2bf(v.x); o.y = f2bf(v.y); o.z = f2bf(v.z); o.w = f2bf(v.w);
    *(ushort4*)(Xb + i) = o;
}

// WpT[n][k] = Wp[k][n]  (512x512)
__global__ void k_prep_wp(const float* __restrict__ Wp, unsigned short* __restrict__ WpT) {
    int idx = blockIdx.x * 256 + threadIdx.x;
    int n = idx >> 9, k = idx & 511;
    WpT[idx] = f2bf(Wp[k * HH + n]);
}

// WtopT[col][k] = Wg[k][hid], UT[col][k] = Wg[H+k][hid]; col = hid*4+g
__global__ void k_prep_u(const float* __restrict__ Wf, const float* __restrict__ Wi,
                         const float* __restrict__ Wc, const float* __restrict__ Wo,
                         const float* __restrict__ bf_, const float* __restrict__ bi_,
                         const float* __restrict__ bc_, const float* __restrict__ bo_,
                         unsigned short* __restrict__ WtopT, unsigned short* __restrict__ UT,
                         float* __restrict__ biascat) {
    int idx = blockIdx.x * 256 + threadIdx.x;   // over NG*512
    int col = idx >> 9, k = idx & 511;
    int g = col & 3, hid = col >> 2;
    const float* W = (g == 0) ? Wf : (g == 1) ? Wi : (g == 2) ? Wc : Wo;
    WtopT[idx] = f2bf(W[k * HH + hid]);
    UT[idx]    = f2bf(W[(HH + k) * HH + hid]);
    if (k == 0) {
        const float* bp = (g == 0) ? bf_ : (g == 1) ? bi_ : (g == 2) ? bc_ : bo_;
        biascat[col] = bp[hid];
    }
}

__global__ void k_zero(unsigned short* __restrict__ hbuf, int* __restrict__ flags) {
    int i = blockIdx.x * 256 + threadIdx.x;   // 128 blocks * 256 = 32768 = 2*BB*HH
    hbuf[i] = 0;
    if (i < 64) flags[i] = 0;
}

// ---------------- phase A: proj = tanh(X @ Wp + bp), stored as 32x32x16 A-fragments ----------------
// projF layout (per t): [ks 0..31][lane 0..63][8 bf16], element (b,h):
//   ks = h>>4, lane = ((h>>3)&1)*32 + b, e = h&7.
// One frag = contiguous 1 KB = one wave-load in the scan.  (PROVEN r2/r3)
__global__ __launch_bounds__(256)
void k_gemm_a1(const unsigned short* __restrict__ A, const unsigned short* __restrict__ BT,
               const float* __restrict__ bias, unsigned short* __restrict__ projF,
               int M, int N, int K) {
    __shared__ unsigned short lA[128 * 32];
    __shared__ unsigned short lB[128 * 32];
    const int tid  = threadIdx.x;
    const int wave = tid >> 6, lane = tid & 63;
    const int q = lane >> 4, ln = lane & 15;
    const int tm = blockIdx.x * 128, tn = blockIdx.y * 128;
    const int mtb = (wave >> 1) * 64, ntb = (wave & 1) * 64;
    f32x4 acc[4][4] = {};

    for (int kc = 0; kc < K; kc += 32) {
        __syncthreads();
        #pragma unroll
        for (int r = 0; r < 2; ++r) {
            int row = r * 64 + wave * 16 + (lane >> 2);
            const unsigned short* ga = A  + (size_t)(tm + row) * K + kc + (lane & 3) * 8;
            const unsigned short* gb = BT + (size_t)(tn + row) * K + kc + (lane & 3) * 8;
            __builtin_amdgcn_global_load_lds(
                (const __attribute__((address_space(1))) uint32_t*)ga,
                (__attribute__((address_space(3))) uint32_t*)&lA[(r * 64 + wave * 16) * 32],
                16, 0, 0);
            __builtin_amdgcn_global_load_lds(
                (const __attribute__((address_space(1))) uint32_t*)gb,
                (__attribute__((address_space(3))) uint32_t*)&lB[(r * 64 + wave * 16) * 32],
                16, 0, 0);
        }
        __syncthreads();
        bf16x8 af[4], bfr[4];
        #pragma unroll
        for (int i = 0; i < 4; ++i) {
            af[i]  = *(const bf16x8*)&lA[(mtb + i * 16 + ln) * 32 + q * 8];
            bfr[i] = *(const bf16x8*)&lB[(ntb + i * 16 + ln) * 32 + q * 8];
        }
        #pragma unroll
        for (int mi = 0; mi < 4; ++mi)
            #pragma unroll
            for (int ni = 0; ni < 4; ++ni)
                acc[mi][ni] = __builtin_amdgcn_mfma_f32_16x16x32_bf16(af[mi], bfr[ni], acc[mi][ni], 0, 0, 0);
    }

    #pragma unroll
    for (int ni = 0; ni < 4; ++ni) {
        int col = tn + ntb + ni * 16 + ln;        // hidden index h, 0..511
        float bz = bias[col];
        int hb2 = (col >> 5) * 1024 + ((col >> 4) & 1) * 512
                + ((col >> 3) & 1) * 256 + (col & 7);   // = ks*512 + hi*256 + e (u16)
        #pragma unroll
        for (int mi = 0; mi < 4; ++mi) {
            #pragma unroll
            for (int r = 0; r < 4; ++r) {
                int row = tm + mtb + mi * 16 + q * 4 + r;  // = b*T + t
                int b = row >> 11, t = row & (TT - 1);
                float v = acc[mi][ni][r] + bz;
                projF[(size_t)t * 16384 + hb2 + b * 8] = f2bf(fast_tanh(v));
            }
        }
    }
}

// ---------------- phase B: persistent recurrent kernel ----------------
// 16 blocks x 512 threads. Block nb owns gate cols [nb*128,+128).
// v5 = r3 structure + the register-residency fix + proj LDS double-buffer:
//   * amdgpu_waves_per_eu(2,2): r1-r3's VGPR_Count of 104-116 proved the allocator was
//     targeting 4 waves/EU (LDS-derived occupancy) and spilling the 128 weight-frag VGPRs,
//     costing ~256KB/block/step of reload traffic (~1.7us of the 6.15us step). Forcing
//     min=max=2 waves/EU raises the cap to 256 VGPRs so weights stay truly resident.
//     TELL: VGPR_Count must come back >=200.
//   * projLds[2] double buffer: proj frags for t+1 prefetched via global_load_lds right
//     BEFORE the spin -> the vmcnt drain at the spin-release barrier overlaps spin slack,
//     and the step-top proj GEMM reads LDS (conflict-free stride-1) with no HBM stall.
//   * dual interleaved MFMA chains (accA/accB, proven r2) halve dependent-chain depth.
// Coherence protocol unchanged (proven r0-r3).
__global__ __launch_bounds__(512) __attribute__((amdgpu_waves_per_eu(2, 2)))
void k_lstm_seq(const unsigned short* __restrict__ projF,  // [T][32 ks][64 lane][8] bf16
                const unsigned short* __restrict__ WtopT,  // [NG][512] bf16
                const unsigned short* __restrict__ UT,     // [NG][512] bf16
                const float* __restrict__ biascat,         // [NG]
                unsigned short* __restrict__ hbuf,         // [2][32 ks][64 lane][8] bf16 frag-major
                int* __restrict__ flags,                   // [16]
                float* __restrict__ out) {                 // [B][T][H] fp32
    const int nb   = blockIdx.x;           // 0..15
    const int tid  = threadIdx.x;          // 0..511
    const int wv   = tid >> 6;             // wave 0..7
    const int l    = tid & 63;
    const int ct   = wv >> 1;              // col-tile 0..3
    const int kh   = wv & 1;               // K-half
    const int lcol = l & 31;
    const int hi   = l >> 5;

    __shared__ __align__(16) unsigned short lh[16384];       // 32KB staged h, frag-major LINEAR
    __shared__ __align__(16) unsigned short projLds[2][16384]; // 2x32KB proj frags, dbl-buffered
    __shared__ float preact[2][32][132];                     // [K-half][batch][local gate col]

    // ---- prologue: stage proj for t=0 into buffer 0 (overlaps weight loading) ----
    {
        const unsigned short* ps = projF + (size_t)(wv * 4) * 512 + l * 8;
        #pragma unroll
        for (int f = 0; f < 4; ++f) {
            __builtin_amdgcn_global_load_lds(
                (const __attribute__((address_space(1))) uint32_t*)(ps + f * 512),
                (__attribute__((address_space(3))) uint32_t*)&projLds[0][(wv * 4 + f) * 512],
                16, 0, 0);
        }
    }

    // B-fragments (weights) for this wave's 32 columns x 16 K-steps. (mapping proven r2)
    const size_t wbase = (size_t)(nb * 128 + ct * 32 + lcol) * 512;
    bf16x8 wtf[16], uf[16];
    #pragma unroll
    for (int j = 0; j < 16; ++j) {
        int ks = kh * 16 + j;
        wtf[j] = *(const bf16x8*)(WtopT + wbase + ks * 16 + hi * 8);
        uf[j]  = *(const bf16x8*)(UT    + wbase + ks * 16 + hi * 8);
    }
    // Pin: opaque to the optimizer => cannot be rematerialized inside the loop.
    #pragma unroll
    for (int j = 0; j < 16; ++j) {
        asm volatile("" : "+v"(wtf[j]));
        asm volatile("" : "+v"(uf[j]));
    }

    // Gate-cell ownership: 2 cells (b0, hl0), (b0, hl0+1) per thread. (proven r2)
    const int b0  = tid >> 4;
    const int hl0 = (tid * 2) & 31;        // even
    float bias8[8];
    #pragma unroll
    for (int k = 0; k < 8; ++k) bias8[k] = biascat[nb * 128 + hl0 * 4 + k];
    float c0 = 0.f, c1 = 0.f;

    // Publish address in frag-major hbuf (u32 units): frag ks = nb*2 + (hl0>>4). (proven r2)
    const int ksc = nb * 2 + (hl0 >> 4);
    const int hic = (hl0 >> 3) & 1;
    const int ec  = hl0 & 7;               // even
    uint32_t* const pub0 = (uint32_t*)hbuf + (size_t)ksc * 256 + (hic * 32 + b0) * 4 + (ec >> 1);

    __syncthreads();   // prologue proj stage complete

    for (int t = 0; t < TT; ++t) {
        const int rb = (t & 1) ^ 1, wb = t & 1;

        // ---- proj_t @ Wtop from LDS (stride-1 frag reads), dual MFMA chains ----
        f32x16 accA = {}, accB = {};
        {
            const char* pb = (const char*)&projLds[t & 1][0] + (kh * 16) * 1024 + l * 16;
            #pragma unroll
            for (int j = 0; j < 16; j += 2) {
                bf16x8 a0 = *(const bf16x8*)(pb + j * 1024);
                bf16x8 a1 = *(const bf16x8*)(pb + (j + 1) * 1024);
                accA = __builtin_amdgcn_mfma_f32_32x32x16_bf16(a0, wtf[j],     accA, 0, 0, 0);
                accB = __builtin_amdgcn_mfma_f32_32x32x16_bf16(a1, wtf[j + 1], accB, 0, 0, 0);
            }
        }

        // ---- prefetch proj for t+1 into the other LDS buffer (drains during spin slack) ----
        if (t + 1 < TT) {
            const unsigned short* ps = projF + (size_t)(t + 1) * 16384 + (size_t)(wv * 4) * 512 + l * 8;
            #pragma unroll
            for (int f = 0; f < 4; ++f) {
                __builtin_amdgcn_global_load_lds(
                    (const __attribute__((address_space(1))) uint32_t*)(ps + f * 512),
                    (__attribute__((address_space(3))) uint32_t*)&projLds[(t + 1) & 1][(wv * 4 + f) * 512],
                    16, 0, 0);
            }
        }

        // ---- wave-0-only spin; barrier releases the block (and drains the prefetch) ----
        if (t > 0 && wv == 0) {
            int v;
            do {
                v = __hip_atomic_load(&flags[l & 15], __ATOMIC_RELAXED, __HIP_MEMORY_SCOPE_AGENT);
            } while (!__all(v >= t));
        }
        __syncthreads();

        // ---- stage h_{t-1} (32KB, frag-major) into LDS: linear coalesced copy ----
        {
            const u64* hb = (const u64*)hbuf + (size_t)rb * 4096;
            u64 st[8];
            #pragma unroll
            for (int r = 0; r < 8; ++r)
                st[r] = __hip_atomic_load(hb + r * 512 + tid, __ATOMIC_RELAXED, __HIP_MEMORY_SCOPE_AGENT);
            u64* lh64 = (u64*)lh;
            #pragma unroll
            for (int r = 0; r < 8; ++r)
                lh64[r * 512 + tid] = st[r];
        }
        __syncthreads();

        // ---- h_{t-1} @ U from LDS: contiguous 1KB frag reads, dual MFMA chains ----
        {
            const char* lbase = (const char*)lh + (kh * 16) * 1024 + l * 16;
            #pragma unroll
            for (int j = 0; j < 16; j += 2) {
                bf16x8 a0 = *(const bf16x8*)(lbase + j * 1024);
                bf16x8 a1 = *(const bf16x8*)(lbase + (j + 1) * 1024);
                accA = __builtin_amdgcn_mfma_f32_32x32x16_bf16(a0, uf[j],     accA, 0, 0, 0);
                accB = __builtin_amdgcn_mfma_f32_32x32x16_bf16(a1, uf[j + 1], accB, 0, 0, 0);
            }
        }

        // ---- write K-half partial: D row = (reg&3) + 8*(reg>>2) + 4*hi, col = lane&31 ----
        #pragma unroll
        for (int reg = 0; reg < 16; ++reg) {
            int b = (reg & 3) + 8 * (reg >> 2) + 4 * hi;
            preact[kh][b][ct * 32 + lcol] = accA[reg] + accB[reg];
        }
        __syncthreads();

        // ---- gates: sum both K-halves + bias for the 2 owned cells ----
        const float* p0 = &preact[0][b0][hl0 * 4];
        const float* p1 = &preact[1][b0][hl0 * 4];
        float f0 = fast_sig (p0[0] + p1[0] + bias8[0]);
        float i0 = fast_sig (p0[1] + p1[1] + bias8[1]);
        float g0 = fast_tanh(p0[2] + p1[2] + bias8[2]);
        float o0 = fast_sig (p0[3] + p1[3] + bias8[3]);
        c0 = f0 * c0 + i0 * g0;
        float h0 = o0 * fast_tanh(c0);

        float f1 = fast_sig (p0[4] + p1[4] + bias8[4]);
        float i1 = fast_sig (p0[5] + p1[5] + bias8[5]);
        float g1 = fast_tanh(p0[6] + p1[6] + bias8[6]);
        float o1 = fast_sig (p0[7] + p1[7] + bias8[7]);
        c1 = f1 * c1 + i1 * g1;
        float h1 = o1 * fast_tanh(c1);

        // ---- h exchange: one u32 write-through store at the frag-major position ----
        uint32_t packed = (uint32_t)f2bf(h0) | ((uint32_t)f2bf(h1) << 16);
        __hip_atomic_store(pub0 + (size_t)wb * 8192, packed,
                           __ATOMIC_RELAXED, __HIP_MEMORY_SCOPE_AGENT);

        __syncthreads();   // barrier drain (vmcnt 0): h stores LLC-visible; preact reads done
        if (tid == 0)
            __hip_atomic_store(&flags[nb], t + 1, __ATOMIC_RELAXED, __HIP_MEMORY_SCOPE_AGENT);

        // ---- output store AFTER publish: off the inter-block critical path ----
        float2 ho; ho.x = h0; ho.y = h1;
        *(float2*)&out[((size_t)b0 * TT + t) * HH + nb * 32 + hl0] = ho;
    }
}

// ---------------- launcher ----------------
extern "C" void kernel_launch(void* const* d_in, const int* in_sizes, int n_in,
                              void* d_out, int out_size, void* d_ws, size_t ws_size,
                              hipStream_t stream) {
    const float* X   = (const float*)d_in[0];
    const float* Wp  = (const float*)d_in[1];
    const float* bp  = (const float*)d_in[2];
    const float* Wf  = (const float*)d_in[3];
    const float* bf_ = (const float*)d_in[4];
    const float* Wi  = (const float*)d_in[5];
    const float* bi_ = (const float*)d_in[6];
    const float* Wc  = (const float*)d_in[7];
    const float* bc_ = (const float*)d_in[8];
    const float* Wo  = (const float*)d_in[9];
    const float* bo_ = (const float*)d_in[10];
    float* out = (float*)d_out;

    char* w = (char*)d_ws;
    auto alloc = [&](size_t bytes) {
        char* p = w;
        w += (bytes + 255) & ~(size_t)255;
        return p;
    };
    unsigned short* projF  = (unsigned short*)alloc((size_t)BB * TT * HH * 2); // 64 MB fragment-major
    unsigned short* WpT    = (unsigned short*)alloc((size_t)DD * HH * 2);      // 0.5 MB
    unsigned short* WtopT  = (unsigned short*)alloc((size_t)NG * HH * 2);      // 2 MB
    unsigned short* UT     = (unsigned short*)alloc((size_t)NG * HH * 2);      // 2 MB
    float*          biascat= (float*)alloc(NG * 4);
    unsigned short* hbuf   = (unsigned short*)alloc(2 * BB * HH * 2);          // frag-major, dbl-buf
    int*            flags  = (int*)alloc(1024);

    // Xb (bf16 X, 64 MB) borrows d_out (128 MB): consumed by k_gemm_a1 before phase B writes out.
    unsigned short* Xb = (unsigned short*)d_out;

    k_convert_x<<<(BB * TT * DD) / (256 * 4), 256, 0, stream>>>(X, Xb);
    k_prep_wp<<<(DD * HH) / 256, 256, 0, stream>>>(Wp, WpT);
    k_prep_u<<<(NG * HH) / 256, 256, 0, stream>>>(Wf, Wi, Wc, Wo, bf_, bi_, bc_, bo_,
                                                  WtopT, UT, biascat);
    k_zero<<<128, 256, 0, stream>>>(hbuf, flags);

    // proj fragment-major = tanh(X @ Wp + bp)
    k_gemm_a1<<<dim3((BB * TT) / 128, HH / 128), 256, 0, stream>>>(Xb, WpT, bp, projF,
                                                                   BB * TT, HH, DD);
    // sequential scan: waves_per_eu(2,2) register-resident weights, LDS-dbuf proj, staged h
    k_lstm_seq<<<16, 512, 0, stream>>>(projF, WtopT, UT, biascat, hbuf, flags, out);
}